// Round 14
// baseline (78.782 us; speedup 1.0000x reference)
//
#include <hip/hip_runtime.h>
#include <hip/hip_bf16.h>
#include <math.h>

#define BDIM 4096
#define DDIM 2048
#define PDIM 128
#define CDIM 10
#define TB   8192   // 2*B

// exp(cos/TEMP) with TEMP=0.5  ->  exp2(cos * 2/ln2)
#define EXP_SCALE 2.8853900817779268f
#define LAMBDA 0.2f
#define EPS 1e-8f

typedef __bf16 bfv8 __attribute__((ext_vector_type(8)));
typedef float  fv4  __attribute__((ext_vector_type(4)));
typedef unsigned short usv8 __attribute__((ext_vector_type(8)));

typedef const __attribute__((address_space(1))) void gvoid_t;
typedef __attribute__((address_space(3))) void lvoid_t;

__device__ __forceinline__ unsigned short f2bf(float f) {
    unsigned int u = __float_as_uint(f);
    u += 0x7FFFu + ((u >> 16) & 1u);      // round-to-nearest-even
    return (unsigned short)(u >> 16);
}

// Fragment order: 16x32 bf16 operand tile stored as 64 lanes x 8 elems (1 KB):
// lane l (l15,lg), elem j holds M[row l15][k lg*8+j].
//
// ws layout (float index) — PEAK 4.016 MB, under the R1-proven 4.06 MB bound:
//  [0]           sup_acc
//  [1]           flag (int)
//  [16 ..)       phat_f  512 grp x 4 ks x 512 bf16 (2 MB)      [16, 524304)
//  [524304 ..)   WpTf 131072 + WcTf 16384 floats (576 KB)      [524304, 671760)
//  [524304 ..)   part [64][8192] f32 (2 MB) — OVERLAPS weights [524304, 1048592)
//                (weights dead after k13; part written only in k3; no zeroing
//                 needed: every slot has exactly one writer per launch)
//  [1048592 ..)  pospart [32][128] f32 (16 KB)                 [1048592, 1052688)

// ---------------- k0: zero the two scalar accumulators ----------------
__global__ void k0_zero(float* __restrict__ ws_f, float* __restrict__ out) {
    if (threadIdx.x == 0) { ws_f[0] = 0.0f; out[0] = 0.0f; }
}

// ---------------- kf: detect int64 label layout ----------------
__global__ void kf_flag(const int* __restrict__ y32, int* __restrict__ flag_out) {
    __shared__ int s_ok;
    if (threadIdx.x == 0) s_ok = 1;
    __syncthreads();
    int ok = 1;
    #pragma unroll
    for (int i = 0; i < 8; ++i) {
        int w = 2 * (threadIdx.x + 256 * i) + 1;   // odd words 1..4095
        if (y32[w] != 0) ok = 0;
    }
    if (!ok) atomicAnd(&s_ok, 0);
    __syncthreads();
    if (threadIdx.x == 0) *flag_out = s_ok;
}

// ---------------- kw: build fragment-ordered bf16 weights ----------------
__global__ __launch_bounds__(256) void kw_prep(
    const float* __restrict__ Wp, const float* __restrict__ Wc,
    unsigned short* __restrict__ WpTf, unsigned short* __restrict__ WcTf)
{
    int idx = blockIdx.x * 256 + threadIdx.x;   // < 36864
    if (idx < 32768) {
        const int l = idx & 63, frag = idx >> 6;
        const int n = frag >> 6, ks2 = frag & 63;
        const int l15 = l & 15, lg = l >> 4;
        usv8 o;
        #pragma unroll
        for (int j = 0; j < 8; ++j)
            o[j] = f2bf(Wp[(size_t)(ks2 * 32 + lg * 8 + j) * PDIM + n * 16 + l15]);
        *(usv8*)&WpTf[(size_t)idx * 8] = o;
    } else {
        const int i2 = idx - 32768;             // < 4096
        const int l = i2 & 63, ks2 = i2 >> 6;
        const int l15 = l & 15, lg = l >> 4;
        usv8 o;
        #pragma unroll
        for (int j = 0; j < 8; ++j)
            o[j] = (l15 < CDIM) ? f2bf(Wc[(size_t)(ks2 * 32 + lg * 8 + j) * CDIM + l15])
                                : (unsigned short)0;
        *(usv8*)&WcTf[(size_t)i2 * 8] = o;
    }
}

// ---------------- k13: fused proj-GEMM + normalize + digits + CE -----------
// VERBATIM from the R11 passing kernel (72.7 µs): 256 blocks x 512 thr,
// 32 rows/block, x staged fp32 via global_load_lds into double-buffered
// swizzled LDS; fragment-ordered B loads; phat written in fragment order.
__global__ __launch_bounds__(512, 2) void k13_fused(
    const float* __restrict__ xi, const float* __restrict__ xj,
    const __bf16* __restrict__ WpTf, const __bf16* __restrict__ WcTf,
    const int* __restrict__ y, const int* __restrict__ flag_p,
    unsigned short* __restrict__ phat_f, float* __restrict__ sup_acc)
{
    __shared__ float Xs[2][32][256];            // 64 KB fp32, swizzled
    __shared__ float sproj[32][132];            // 16.9 KB
    __shared__ float sdig[2][4][16][16];        // 8 KB
    __shared__ float sce[32];

    const int tid = threadIdx.x;
    const int wv = tid >> 6, lane = tid & 63;
    const int l15 = lane & 15, lg = lane >> 4;
    const int wr = wv >> 2, wc = wv & 3;
    const int R0 = blockIdx.x * 32;
    const float* src = (R0 < BDIM) ? (xi + (size_t)R0 * DDIM)
                                   : (xj + (size_t)(R0 - BDIM) * DDIM);
    const int swzr = l15 << 4;                  // a-frag read swizzle

    fv4 acc0 = {}, acc1 = {}, accd = {};

    #define STAGE(KT, BUF)                                                     \
        {                                                                      \
            _Pragma("unroll")                                                  \
            for (int q = 0; q < 4; ++q) {                                      \
                const int r_ = wv * 4 + q;                                     \
                const char* g_ = (const char*)src + (size_t)r_ * (DDIM * 4)    \
                               + (KT) * 1024 + ((lane * 16) ^ ((r_ & 15) << 4)); \
                __builtin_amdgcn_global_load_lds((gvoid_t*)g_,                 \
                    (lvoid_t*)&Xs[BUF][r_][0], 16, 0, 0);                      \
            }                                                                  \
        }

    STAGE(0, 0)

    for (int kt = 0; kt < 8; ++kt) {
        __syncthreads();              // drains vmcnt: tile kt fully staged
        if (kt < 7) STAGE(kt + 1, (kt + 1) & 1)

        const char* xb = (const char*)&Xs[kt & 1][0][0] + (wr * 16 + l15) * 1024;

        // fragment-ordered B: coalesced 1 KB loads, all issued up front
        bfv8 b0[8], b1[8];
        #pragma unroll
        for (int s = 0; s < 8; ++s) {
            b0[s] = *(const bfv8*)(WpTf + (size_t)(((2 * wc) * 64 + kt * 8 + s) * 512) + lane * 8);
            b1[s] = *(const bfv8*)(WpTf + (size_t)(((2 * wc + 1) * 64 + kt * 8 + s) * 512) + lane * 8);
        }
        bfv8 bd0 = *(const bfv8*)(WcTf + (size_t)((kt * 8 + wc) * 512) + lane * 8);
        bfv8 bd1 = *(const bfv8*)(WcTf + (size_t)((kt * 8 + wc + 4) * 512) + lane * 8);

        #pragma unroll
        for (int s = 0; s < 8; ++s) {
            fv4 x0 = *(const fv4*)(xb + ((s * 128 + lg * 32) ^ swzr));
            fv4 x1 = *(const fv4*)(xb + ((s * 128 + lg * 32 + 16) ^ swzr));
            usv8 au;
            au[0] = f2bf(x0[0]); au[1] = f2bf(x0[1]);
            au[2] = f2bf(x0[2]); au[3] = f2bf(x0[3]);
            au[4] = f2bf(x1[0]); au[5] = f2bf(x1[1]);
            au[6] = f2bf(x1[2]); au[7] = f2bf(x1[3]);
            bfv8 a = __builtin_bit_cast(bfv8, au);
            acc0 = __builtin_amdgcn_mfma_f32_16x16x32_bf16(a, b0[s], acc0, 0, 0, 0);
            acc1 = __builtin_amdgcn_mfma_f32_16x16x32_bf16(a, b1[s], acc1, 0, 0, 0);
            if (s == wc)
                accd = __builtin_amdgcn_mfma_f32_16x16x32_bf16(a, bd0, accd, 0, 0, 0);
            if (s == wc + 4)
                accd = __builtin_amdgcn_mfma_f32_16x16x32_bf16(a, bd1, accd, 0, 0, 0);
        }
    }
    #undef STAGE

    // scatter: C layout row=lg*4+r, col=l15
    #pragma unroll
    for (int r = 0; r < 4; ++r) {
        sproj[wr * 16 + lg * 4 + r][wc * 32 + l15]      = acc0[r];
        sproj[wr * 16 + lg * 4 + r][wc * 32 + 16 + l15] = acc1[r];
    }
    #pragma unroll
    for (int r = 0; r < 4; ++r)
        sdig[wr][wc][lg * 4 + r][l15] = accd[r];
    __syncthreads();

    // ---- proj: rsqrt-normalize rows, write bf16 phat (fragment order) ----
    {
        const int row = tid >> 4;            // 0..31, 16 threads per row
        const int c8  = (tid & 15) * 8;
        fv4 p0 = *(const fv4*)&sproj[row][c8];
        fv4 p1 = *(const fv4*)&sproj[row][c8 + 4];
        float ssq = p0[0]*p0[0] + p0[1]*p0[1] + p0[2]*p0[2] + p0[3]*p0[3]
                  + p1[0]*p1[0] + p1[1]*p1[1] + p1[2]*p1[2] + p1[3]*p1[3];
        #pragma unroll
        for (int m = 8; m >= 1; m >>= 1) ssq += __shfl_xor(ssq, m, 64);
        float rn = rsqrtf(ssq);
        usv8 pk;
        pk[0] = f2bf(p0[0]*rn); pk[1] = f2bf(p0[1]*rn);
        pk[2] = f2bf(p0[2]*rn); pk[3] = f2bf(p0[3]*rn);
        pk[4] = f2bf(p1[0]*rn); pk[5] = f2bf(p1[1]*rn);
        pk[6] = f2bf(p1[2]*rn); pk[7] = f2bf(p1[3]*rn);
        const int grow = R0 + row;
        const int g = grow >> 4, lr = grow & 15;
        const int ks = c8 >> 5, lgw = (c8 >> 3) & 3;
        *(usv8*)&phat_f[(size_t)((g * 4 + ks) * 512 + (lgw * 16 + lr) * 8)] = pk;
    }

    // ---- digits: sum 4 wc-slabs per half, CE via 16-lane shuffles ----
    {
        const int drow = tid >> 4;           // 0..31
        const int dc   = tid & 15;           // cols 10..15 zero-pad
        float d = 0.0f;
        #pragma unroll
        for (int q = 0; q < 4; ++q) d += sdig[drow >> 4][q][drow & 15][dc];
        float dv = (dc < CDIM) ? d : -1e30f;
        float mx = dv;
        #pragma unroll
        for (int m = 8; m >= 1; m >>= 1) mx = fmaxf(mx, __shfl_xor(mx, m, 64));
        float e = (dc < CDIM) ? __expf(d - mx) : 0.0f;
        float s = e;
        #pragma unroll
        for (int m = 8; m >= 1; m >>= 1) s += __shfl_xor(s, m, 64);
        const int rowg = R0 + drow;
        const int idx  = rowg & (BDIM - 1);
        const int label = (*flag_p) ? y[2 * idx] : y[idx];
        float dl = (dc == label) ? d : 0.0f;
        #pragma unroll
        for (int m = 8; m >= 1; m >>= 1) dl += __shfl_xor(dl, m, 64);
        if (dc == 0) sce[drow] = (mx + __logf(s)) - dl;
    }
    __syncthreads();
    if (tid == 0) {
        float t = 0.0f;
        #pragma unroll
        for (int r = 0; r < 32; ++r) t += sce[r];
        atomicAdd(sup_acc, t * (1.0f / BDIM));
    }
}

// ---------------- k3: Gram row-sum via bf16 MFMA (upper-triangle tiles) ----
// R11 body verbatim; ONLY the tail changed: atomicAdd(rowsum/possum) ->
// plain stores into part/pospart (single writer per slot, proven by the
// triangle decomposition: slab = other tile coordinate = column panel).
__global__ __launch_bounds__(256) void k3_gram_mfma(
    const __bf16* __restrict__ pf,
    float* __restrict__ part, float* __restrict__ pospart)
{
    __shared__ float srow[128 * 37 + 4];   // [row][wc*16+l15], stride 37
    __shared__ float scol[128 * 9 + 4];    // [col][wr*4+lg],  stride 9
    __shared__ float spos[128];
    const int tid = threadIdx.x;

    int t = blockIdx.x;
    int ti = 0;
    while (t >= 64 - ti) { t -= 64 - ti; ++ti; }
    const int tj = ti + t;
    const int I0 = ti * 128, J0 = tj * 128;
    const bool diag    = (ti == tj);
    const bool partner = (tj == ti + 32);

    if (tid < 128) spos[tid] = 0.0f;
    __syncthreads();

    const int wid = tid >> 6, lane = tid & 63;
    const int wr = wid >> 1, wc = wid & 1;
    const int l15 = lane & 15, lg = lane >> 4;

    fv4 acc[4][4] = {};
    #pragma unroll
    for (int ks = 0; ks < 4; ++ks) {
        bfv8 a[4], b[4];
        #pragma unroll
        for (int m = 0; m < 4; ++m)
            a[m] = *(const bfv8*)(pf + (size_t)(((ti * 8 + wr * 4 + m) * 4 + ks) * 512) + lane * 8);
        #pragma unroll
        for (int n = 0; n < 4; ++n)
            b[n] = *(const bfv8*)(pf + (size_t)(((tj * 8 + wc * 4 + n) * 4 + ks) * 512) + lane * 8);
        #pragma unroll
        for (int m = 0; m < 4; ++m)
            #pragma unroll
            for (int n = 0; n < 4; ++n)
                acc[m][n] = __builtin_amdgcn_mfma_f32_16x16x32_bf16(a[m], b[n], acc[m][n], 0, 0, 0);
    }

    // epilogue: exp, diag-mask, per-lane row/col partials
    float rs_l[4][4];
    float cs_l[4] = {0, 0, 0, 0};
    #pragma unroll
    for (int m = 0; m < 4; ++m)
        #pragma unroll
        for (int r = 0; r < 4; ++r) rs_l[m][r] = 0.0f;

    #pragma unroll
    for (int m = 0; m < 4; ++m) {
        const int ribase = wr * 64 + m * 16 + lg * 4;
        #pragma unroll
        for (int n = 0; n < 4; ++n) {
            const int cj = wc * 64 + n * 16 + l15;
            #pragma unroll
            for (int r = 0; r < 4; ++r) {
                const int ri = ribase + r;
                float e = exp2f(acc[m][n][r] * EXP_SCALE);
                if (diag && ri == cj) e = 0.0f;
                rs_l[m][r] += e;
                cs_l[n] += e;
                if (partner && ri == cj) atomicAdd(&spos[ri], e);
            }
        }
    }

    // scatter partials (each slot written by exactly one lane)
    #pragma unroll
    for (int m = 0; m < 4; ++m)
        #pragma unroll
        for (int r = 0; r < 4; ++r)
            srow[(wr * 64 + m * 16 + lg * 4 + r) * 37 + wc * 16 + l15] = rs_l[m][r];
    #pragma unroll
    for (int n = 0; n < 4; ++n)
        scol[(wc * 64 + n * 16 + l15) * 9 + wr * 4 + lg] = cs_l[n];
    __syncthreads();

    // gather + plain stores (no global atomics)
    if (tid < 128) {
        float s = 0.0f;
        #pragma unroll
        for (int q = 0; q < 32; ++q) s += srow[tid * 37 + q];
        part[(size_t)tj * TB + I0 + tid] = s;
        if (partner) pospart[ti * 128 + tid] = spos[tid];
    } else if (!diag) {
        const int col = tid - 128;
        float s = 0.0f;
        #pragma unroll
        for (int q = 0; q < 8; ++q) s += scol[col * 9 + q];
        part[(size_t)ti * TB + J0 + col] = s;
    }
}

// ---------------- k4: gather partials + final reduction (32 blocks) --------
__global__ __launch_bounds__(256) void k4_final(
    const float* __restrict__ part, const float* __restrict__ pospart,
    const float* __restrict__ sup_acc, float* __restrict__ out)
{
    __shared__ float red[4];
    const int tid = threadIdx.x;
    const int r = blockIdx.x * 256 + tid;
    float rs = 0.0f;
    #pragma unroll 8
    for (int t = 0; t < 64; ++t) rs += part[(size_t)t * TB + r];
    const float pos = pospart[((r & (BDIM - 1)) >> 7) * 128 + (r & 127)];
    float s = -__logf(pos / rs + EPS);
    #pragma unroll
    for (int m = 32; m >= 1; m >>= 1) s += __shfl_xor(s, m, 64);
    if ((tid & 63) == 0) red[tid >> 6] = s;
    __syncthreads();
    if (tid == 0) {
        float p = (red[0] + red[1] + red[2] + red[3]) * (1.0f / TB);
        if (blockIdx.x == 0) p += LAMBDA * sup_acc[0];
        atomicAdd(out, p);
    }
}

extern "C" void kernel_launch(void* const* d_in, const int* in_sizes, int n_in,
                              void* d_out, int out_size, void* d_ws, size_t ws_size,
                              hipStream_t stream) {
    const float* xi = (const float*)d_in[1];
    const float* xj = (const float*)d_in[2];
    const int*   y  = (const int*)d_in[3];
    const float* Wp = (const float*)d_in[4];
    const float* Wc = (const float*)d_in[5];
    float* out  = (float*)d_out;

    float* ws_f   = (float*)d_ws;
    float* sup    = ws_f;
    int*   flag   = (int*)(ws_f + 1);
    unsigned short* phat_u = (unsigned short*)(ws_f + 16);
    unsigned short* WpTf_u = (unsigned short*)(ws_f + 524304);
    unsigned short* WcTf_u = (unsigned short*)(ws_f + 655376);
    float* part    = ws_f + 524304;     // overlaps weights (dead after k13)
    float* pospart = ws_f + 1048592;

    k0_zero<<<1, 64, 0, stream>>>(ws_f, out);
    kf_flag<<<1, 256, 0, stream>>>(y, flag);
    kw_prep<<<144, 256, 0, stream>>>(Wp, Wc, WpTf_u, WcTf_u);
    k13_fused<<<256, 512, 0, stream>>>(xi, xj, (const __bf16*)WpTf_u, (const __bf16*)WcTf_u,
                                       y, flag, phat_u, sup);
    k3_gram_mfma<<<2080, 256, 0, stream>>>((const __bf16*)phat_u, part, pospart);
    k4_final<<<32, 256, 0, stream>>>(part, pospart, sup, out);
}

// Round 15
// 75.759 us; speedup vs baseline: 1.0399x; 1.0399x over previous
//
#include <hip/hip_runtime.h>
#include <hip/hip_bf16.h>
#include <math.h>

#define BDIM 4096
#define DDIM 2048
#define PDIM 128
#define CDIM 10
#define TB   8192   // 2*B

// exp(cos/TEMP) with TEMP=0.5  ->  exp2(cos * 2/ln2)
#define EXP_SCALE 2.8853900817779268f
#define LAMBDA 0.2f
#define EPS 1e-8f

typedef __bf16 bfv8 __attribute__((ext_vector_type(8)));
typedef float  fv4  __attribute__((ext_vector_type(4)));
typedef unsigned short usv8 __attribute__((ext_vector_type(8)));

typedef const __attribute__((address_space(1))) void gvoid_t;
typedef __attribute__((address_space(3))) void lvoid_t;

__device__ __forceinline__ unsigned short f2bf(float f) {
    unsigned int u = __float_as_uint(f);
    u += 0x7FFFu + ((u >> 16) & 1u);      // round-to-nearest-even
    return (unsigned short)(u >> 16);
}

// Fragment order: 16x32 bf16 operand tile stored as 64 lanes x 8 elems (1 KB):
// lane l (l15,lg), elem j holds M[row l15][k lg*8+j].
//
// ws layout (float index) — PEAK 4.016 MB:
//  [0]           sup_acc
//  [1]           flag (int)
//  [16 ..)       phat_f  512 grp x 4 ks x 512 bf16 (2 MB)      [16, 524304)
//  [524304 ..)   WpTf 131072 + WcTf 16384 floats (576 KB)      [524304, 671760)
//  [524304 ..)   part [64][8192] f32 (2 MB) — OVERLAPS weights (dead after k13)
//  [1048592 ..)  pospart [32][128] f32 (16 KB)

// ---------------- k0: zero the two scalar accumulators ----------------
__global__ void k0_zero(float* __restrict__ ws_f, float* __restrict__ out) {
    if (threadIdx.x == 0) { ws_f[0] = 0.0f; out[0] = 0.0f; }
}

// ---------------- kf: detect int64 label layout ----------------
__global__ void kf_flag(const int* __restrict__ y32, int* __restrict__ flag_out) {
    __shared__ int s_ok;
    if (threadIdx.x == 0) s_ok = 1;
    __syncthreads();
    int ok = 1;
    #pragma unroll
    for (int i = 0; i < 8; ++i) {
        int w = 2 * (threadIdx.x + 256 * i) + 1;   // odd words 1..4095
        if (y32[w] != 0) ok = 0;
    }
    if (!ok) atomicAnd(&s_ok, 0);
    __syncthreads();
    if (threadIdx.x == 0) *flag_out = s_ok;
}

// ---------------- kw: build fragment-ordered bf16 weights ----------------
__global__ __launch_bounds__(256) void kw_prep(
    const float* __restrict__ Wp, const float* __restrict__ Wc,
    unsigned short* __restrict__ WpTf, unsigned short* __restrict__ WcTf)
{
    int idx = blockIdx.x * 256 + threadIdx.x;   // < 36864
    if (idx < 32768) {
        const int l = idx & 63, frag = idx >> 6;
        const int n = frag >> 6, ks2 = frag & 63;
        const int l15 = l & 15, lg = l >> 4;
        usv8 o;
        #pragma unroll
        for (int j = 0; j < 8; ++j)
            o[j] = f2bf(Wp[(size_t)(ks2 * 32 + lg * 8 + j) * PDIM + n * 16 + l15]);
        *(usv8*)&WpTf[(size_t)idx * 8] = o;
    } else {
        const int i2 = idx - 32768;             // < 4096
        const int l = i2 & 63, ks2 = i2 >> 6;
        const int l15 = l & 15, lg = l >> 4;
        usv8 o;
        #pragma unroll
        for (int j = 0; j < 8; ++j)
            o[j] = (l15 < CDIM) ? f2bf(Wc[(size_t)(ks2 * 32 + lg * 8 + j) * CDIM + l15])
                                : (unsigned short)0;
        *(usv8*)&WcTf[(size_t)i2 * 8] = o;
    }
}

// ---------------- k13: fused proj-GEMM + normalize + digits + CE -----------
// R14 structure; ONE change: within each kt iteration the L2 B-frag loads
// are issued BEFORE the HBM global_load_lds prefetch. vmcnt is ordered, so
// with STAGE issued first, consuming B drained the STAGE too (~900cy HBM
// round-trip exposed per iteration). Issued last, the compiler can emit
// s_waitcnt vmcnt(4) for B-use, leaving the 4 STAGE loads in flight under
// the whole compute phase (m218 counted-vmcnt pattern, by issue order).
__global__ __launch_bounds__(512, 2) void k13_fused(
    const float* __restrict__ xi, const float* __restrict__ xj,
    const __bf16* __restrict__ WpTf, const __bf16* __restrict__ WcTf,
    const int* __restrict__ y, const int* __restrict__ flag_p,
    unsigned short* __restrict__ phat_f, float* __restrict__ sup_acc)
{
    __shared__ float Xs[2][32][256];            // 64 KB fp32, swizzled
    __shared__ float sproj[32][132];            // 16.9 KB
    __shared__ float sdig[2][4][16][16];        // 8 KB
    __shared__ float sce[32];

    const int tid = threadIdx.x;
    const int wv = tid >> 6, lane = tid & 63;
    const int l15 = lane & 15, lg = lane >> 4;
    const int wr = wv >> 2, wc = wv & 3;
    const int R0 = blockIdx.x * 32;
    const float* src = (R0 < BDIM) ? (xi + (size_t)R0 * DDIM)
                                   : (xj + (size_t)(R0 - BDIM) * DDIM);
    const int swzr = l15 << 4;                  // a-frag read swizzle

    fv4 acc0 = {}, acc1 = {}, accd = {};

    #define STAGE(KT, BUF)                                                     \
        {                                                                      \
            _Pragma("unroll")                                                  \
            for (int q = 0; q < 4; ++q) {                                      \
                const int r_ = wv * 4 + q;                                     \
                const char* g_ = (const char*)src + (size_t)r_ * (DDIM * 4)    \
                               + (KT) * 1024 + ((lane * 16) ^ ((r_ & 15) << 4)); \
                __builtin_amdgcn_global_load_lds((gvoid_t*)g_,                 \
                    (lvoid_t*)&Xs[BUF][r_][0], 16, 0, 0);                      \
            }                                                                  \
        }

    STAGE(0, 0)

    for (int kt = 0; kt < 8; ++kt) {
        __syncthreads();              // drains vmcnt: tile kt fully staged

        // B-frag loads FIRST (L2-resident, consumed this iteration)
        bfv8 b0[8], b1[8];
        #pragma unroll
        for (int s = 0; s < 8; ++s) {
            b0[s] = *(const bfv8*)(WpTf + (size_t)(((2 * wc) * 64 + kt * 8 + s) * 512) + lane * 8);
            b1[s] = *(const bfv8*)(WpTf + (size_t)(((2 * wc + 1) * 64 + kt * 8 + s) * 512) + lane * 8);
        }
        bfv8 bd0 = *(const bfv8*)(WcTf + (size_t)((kt * 8 + wc) * 512) + lane * 8);
        bfv8 bd1 = *(const bfv8*)(WcTf + (size_t)((kt * 8 + wc + 4) * 512) + lane * 8);

        // HBM prefetch LAST (youngest in vmcnt queue; drained at next barrier)
        if (kt < 7) STAGE(kt + 1, (kt + 1) & 1)

        const char* xb = (const char*)&Xs[kt & 1][0][0] + (wr * 16 + l15) * 1024;

        #pragma unroll
        for (int s = 0; s < 8; ++s) {
            fv4 x0 = *(const fv4*)(xb + ((s * 128 + lg * 32) ^ swzr));
            fv4 x1 = *(const fv4*)(xb + ((s * 128 + lg * 32 + 16) ^ swzr));
            usv8 au;
            au[0] = f2bf(x0[0]); au[1] = f2bf(x0[1]);
            au[2] = f2bf(x0[2]); au[3] = f2bf(x0[3]);
            au[4] = f2bf(x1[0]); au[5] = f2bf(x1[1]);
            au[6] = f2bf(x1[2]); au[7] = f2bf(x1[3]);
            bfv8 a = __builtin_bit_cast(bfv8, au);
            acc0 = __builtin_amdgcn_mfma_f32_16x16x32_bf16(a, b0[s], acc0, 0, 0, 0);
            acc1 = __builtin_amdgcn_mfma_f32_16x16x32_bf16(a, b1[s], acc1, 0, 0, 0);
            if (s == wc)
                accd = __builtin_amdgcn_mfma_f32_16x16x32_bf16(a, bd0, accd, 0, 0, 0);
            if (s == wc + 4)
                accd = __builtin_amdgcn_mfma_f32_16x16x32_bf16(a, bd1, accd, 0, 0, 0);
        }
    }
    #undef STAGE

    // scatter: C layout row=lg*4+r, col=l15
    #pragma unroll
    for (int r = 0; r < 4; ++r) {
        sproj[wr * 16 + lg * 4 + r][wc * 32 + l15]      = acc0[r];
        sproj[wr * 16 + lg * 4 + r][wc * 32 + 16 + l15] = acc1[r];
    }
    #pragma unroll
    for (int r = 0; r < 4; ++r)
        sdig[wr][wc][lg * 4 + r][l15] = accd[r];
    __syncthreads();

    // ---- proj: rsqrt-normalize rows, write bf16 phat (fragment order) ----
    {
        const int row = tid >> 4;            // 0..31, 16 threads per row
        const int c8  = (tid & 15) * 8;
        fv4 p0 = *(const fv4*)&sproj[row][c8];
        fv4 p1 = *(const fv4*)&sproj[row][c8 + 4];
        float ssq = p0[0]*p0[0] + p0[1]*p0[1] + p0[2]*p0[2] + p0[3]*p0[3]
                  + p1[0]*p1[0] + p1[1]*p1[1] + p1[2]*p1[2] + p1[3]*p1[3];
        #pragma unroll
        for (int m = 8; m >= 1; m >>= 1) ssq += __shfl_xor(ssq, m, 64);
        float rn = rsqrtf(ssq);
        usv8 pk;
        pk[0] = f2bf(p0[0]*rn); pk[1] = f2bf(p0[1]*rn);
        pk[2] = f2bf(p0[2]*rn); pk[3] = f2bf(p0[3]*rn);
        pk[4] = f2bf(p1[0]*rn); pk[5] = f2bf(p1[1]*rn);
        pk[6] = f2bf(p1[2]*rn); pk[7] = f2bf(p1[3]*rn);
        const int grow = R0 + row;
        const int g = grow >> 4, lr = grow & 15;
        const int ks = c8 >> 5, lgw = (c8 >> 3) & 3;
        *(usv8*)&phat_f[(size_t)((g * 4 + ks) * 512 + (lgw * 16 + lr) * 8)] = pk;
    }

    // ---- digits: sum 4 wc-slabs per half, CE via 16-lane shuffles ----
    {
        const int drow = tid >> 4;           // 0..31
        const int dc   = tid & 15;           // cols 10..15 zero-pad
        float d = 0.0f;
        #pragma unroll
        for (int q = 0; q < 4; ++q) d += sdig[drow >> 4][q][drow & 15][dc];
        float dv = (dc < CDIM) ? d : -1e30f;
        float mx = dv;
        #pragma unroll
        for (int m = 8; m >= 1; m >>= 1) mx = fmaxf(mx, __shfl_xor(mx, m, 64));
        float e = (dc < CDIM) ? __expf(d - mx) : 0.0f;
        float s = e;
        #pragma unroll
        for (int m = 8; m >= 1; m >>= 1) s += __shfl_xor(s, m, 64);
        const int rowg = R0 + drow;
        const int idx  = rowg & (BDIM - 1);
        const int label = (*flag_p) ? y[2 * idx] : y[idx];
        float dl = (dc == label) ? d : 0.0f;
        #pragma unroll
        for (int m = 8; m >= 1; m >>= 1) dl += __shfl_xor(dl, m, 64);
        if (dc == 0) sce[drow] = (mx + __logf(s)) - dl;
    }
    __syncthreads();
    if (tid == 0) {
        float t = 0.0f;
        #pragma unroll
        for (int r = 0; r < 32; ++r) t += sce[r];
        atomicAdd(sup_acc, t * (1.0f / BDIM));
    }
}

// ---------------- k3: Gram row-sum via bf16 MFMA (upper-triangle tiles) ----
// R14 body; ONE change: XCD-aware bijective block swizzle (2080 = 8*260) —
// each XCD's 260 consecutive triangle tiles share A/B panels in its private
// 4 MB L2 (phat is 2 MB, fully L2-resident per XCD).
__global__ __launch_bounds__(256) void k3_gram_mfma(
    const __bf16* __restrict__ pf,
    float* __restrict__ part, float* __restrict__ pospart)
{
    __shared__ float srow[128 * 37 + 4];   // [row][wc*16+l15], stride 37
    __shared__ float scol[128 * 9 + 4];    // [col][wr*4+lg],  stride 9
    __shared__ float spos[128];
    const int tid = threadIdx.x;

    int t = (blockIdx.x & 7) * 260 + (blockIdx.x >> 3);   // XCD swizzle
    int ti = 0;
    while (t >= 64 - ti) { t -= 64 - ti; ++ti; }
    const int tj = ti + t;
    const int I0 = ti * 128, J0 = tj * 128;
    const bool diag    = (ti == tj);
    const bool partner = (tj == ti + 32);

    if (tid < 128) spos[tid] = 0.0f;
    __syncthreads();

    const int wid = tid >> 6, lane = tid & 63;
    const int wr = wid >> 1, wc = wid & 1;
    const int l15 = lane & 15, lg = lane >> 4;

    fv4 acc[4][4] = {};
    #pragma unroll
    for (int ks = 0; ks < 4; ++ks) {
        bfv8 a[4], b[4];
        #pragma unroll
        for (int m = 0; m < 4; ++m)
            a[m] = *(const bfv8*)(pf + (size_t)(((ti * 8 + wr * 4 + m) * 4 + ks) * 512) + lane * 8);
        #pragma unroll
        for (int n = 0; n < 4; ++n)
            b[n] = *(const bfv8*)(pf + (size_t)(((tj * 8 + wc * 4 + n) * 4 + ks) * 512) + lane * 8);
        #pragma unroll
        for (int m = 0; m < 4; ++m)
            #pragma unroll
            for (int n = 0; n < 4; ++n)
                acc[m][n] = __builtin_amdgcn_mfma_f32_16x16x32_bf16(a[m], b[n], acc[m][n], 0, 0, 0);
    }

    // epilogue: exp, diag-mask, per-lane row/col partials
    float rs_l[4][4];
    float cs_l[4] = {0, 0, 0, 0};
    #pragma unroll
    for (int m = 0; m < 4; ++m)
        #pragma unroll
        for (int r = 0; r < 4; ++r) rs_l[m][r] = 0.0f;

    #pragma unroll
    for (int m = 0; m < 4; ++m) {
        const int ribase = wr * 64 + m * 16 + lg * 4;
        #pragma unroll
        for (int n = 0; n < 4; ++n) {
            const int cj = wc * 64 + n * 16 + l15;
            #pragma unroll
            for (int r = 0; r < 4; ++r) {
                const int ri = ribase + r;
                float e = exp2f(acc[m][n][r] * EXP_SCALE);
                if (diag && ri == cj) e = 0.0f;
                rs_l[m][r] += e;
                cs_l[n] += e;
                if (partner && ri == cj) atomicAdd(&spos[ri], e);
            }
        }
    }

    // scatter partials (each slot written by exactly one lane)
    #pragma unroll
    for (int m = 0; m < 4; ++m)
        #pragma unroll
        for (int r = 0; r < 4; ++r)
            srow[(wr * 64 + m * 16 + lg * 4 + r) * 37 + wc * 16 + l15] = rs_l[m][r];
    #pragma unroll
    for (int n = 0; n < 4; ++n)
        scol[(wc * 64 + n * 16 + l15) * 9 + wr * 4 + lg] = cs_l[n];
    __syncthreads();

    // gather + plain stores (no global atomics; single writer per slot)
    if (tid < 128) {
        float s = 0.0f;
        #pragma unroll
        for (int q = 0; q < 32; ++q) s += srow[tid * 37 + q];
        part[(size_t)tj * TB + I0 + tid] = s;
        if (partner) pospart[ti * 128 + tid] = spos[tid];
    } else if (!diag) {
        const int col = tid - 128;
        float s = 0.0f;
        #pragma unroll
        for (int q = 0; q < 8; ++q) s += scol[col * 9 + q];
        part[(size_t)ti * TB + J0 + col] = s;
    }
}

// ---------------- k4: gather partials + final reduction (32 blocks) --------
__global__ __launch_bounds__(256) void k4_final(
    const float* __restrict__ part, const float* __restrict__ pospart,
    const float* __restrict__ sup_acc, float* __restrict__ out)
{
    __shared__ float red[4];
    const int tid = threadIdx.x;
    const int r = blockIdx.x * 256 + tid;
    float rs = 0.0f;
    #pragma unroll 8
    for (int t = 0; t < 64; ++t) rs += part[(size_t)t * TB + r];
    const float pos = pospart[((r & (BDIM - 1)) >> 7) * 128 + (r & 127)];
    float s = -__logf(pos / rs + EPS);
    #pragma unroll
    for (int m = 32; m >= 1; m >>= 1) s += __shfl_xor(s, m, 64);
    if ((tid & 63) == 0) red[tid >> 6] = s;
    __syncthreads();
    if (tid == 0) {
        float p = (red[0] + red[1] + red[2] + red[3]) * (1.0f / TB);
        if (blockIdx.x == 0) p += LAMBDA * sup_acc[0];
        atomicAdd(out, p);
    }
}

extern "C" void kernel_launch(void* const* d_in, const int* in_sizes, int n_in,
                              void* d_out, int out_size, void* d_ws, size_t ws_size,
                              hipStream_t stream) {
    const float* xi = (const float*)d_in[1];
    const float* xj = (const float*)d_in[2];
    const int*   y  = (const int*)d_in[3];
    const float* Wp = (const float*)d_in[4];
    const float* Wc = (const float*)d_in[5];
    float* out  = (float*)d_out;

    float* ws_f   = (float*)d_ws;
    float* sup    = ws_f;
    int*   flag   = (int*)(ws_f + 1);
    unsigned short* phat_u = (unsigned short*)(ws_f + 16);
    unsigned short* WpTf_u = (unsigned short*)(ws_f + 524304);
    unsigned short* WcTf_u = (unsigned short*)(ws_f + 655376);
    float* part    = ws_f + 524304;     // overlaps weights (dead after k13)
    float* pospart = ws_f + 1048592;

    k0_zero<<<1, 64, 0, stream>>>(ws_f, out);
    kf_flag<<<1, 256, 0, stream>>>(y, flag);
    kw_prep<<<144, 256, 0, stream>>>(Wp, Wc, WpTf_u, WcTf_u);
    k13_fused<<<256, 512, 0, stream>>>(xi, xj, (const __bf16*)WpTf_u, (const __bf16*)WcTf_u,
                                       y, flag, phat_u, sup);
    k3_gram_mfma<<<2080, 256, 0, stream>>>((const __bf16*)phat_u, part, pospart);
    k4_final<<<32, 256, 0, stream>>>(part, pospart, sup, out);
}